// Round 2
// baseline (375.670 us; speedup 1.0000x reference)
//
#include <hip/hip_runtime.h>
#include <cstdint>
#include <cmath>

// ---------------------------------------------------------------------------
// LlamaAttention round 9: software-pipeline the flash kernel.
//   B=2 L=2048 D=2048 H=16 KV=4 DH=128, causal + key-padding mask, RoPE.
// R8 POST-MORTEM: bank-conflict fix + register-P raised MfmaUtil 15->22% but
//   dur flat at 96us. Real stall: loads issued right before __syncthreads,
//   which hipcc lowers with a FULL vmcnt(0) drain => every round pays whole
//   HBM latency at the barrier with no compute in between (guide m131-141).
// R9 changes (flash only):
//   1. Double-buffered K/V LDS (2x32KB) + ONE raw s_barrier per round with
//      manual "s_waitcnt lgkmcnt(0)" (no vmcnt drain). Loads for round r+2
//      issued at end of round r; consumed (ds_write) at end of round r+1
//      => full round of compute hides HBM latency (T14/T3-minimum).
//   2. Bias row staged in LDS once per block (8KB) so staged K/V loads are
//      the only in-loop VMEM ops; bias reads become LDS broadcasts.
//   3. s_setprio(1) around MFMA clusters (T5; waves now have role diversity).
// Kept from R8: XOR-swizzled K/V LDS, register-resident P via K=16 PV MFMA,
//   exp2-domain softmax (Q pre-scaled), defer-max, c/15-c block pairing.
// MFMA layouts (learn_hip m89/m91): A[m=l15][k], B[k][n=l15],
//   C/D: col=l15, row=quad*4+reg (shape-determined).
// ---------------------------------------------------------------------------

typedef __bf16 bf16_t;
typedef __bf16 bf16x8 __attribute__((ext_vector_type(8)));
typedef __bf16 bf16x4 __attribute__((ext_vector_type(4)));
typedef float  f32x4  __attribute__((ext_vector_type(4)));

#define HQ   16
#define HKV  4
#define GQA  4
#define DHD  128
#define BB   2
#define LL   2048
#define DDIM 2048
#define MINV (-1e15f)
// 1/sqrt(128) * log2(e): folded into Q at RoPE time so softmax uses exp2.
#define QSC  0.12751744f

static __device__ __forceinline__ f32x4 mfma16(bf16x8 a, bf16x8 b, f32x4 c) {
  return __builtin_amdgcn_mfma_f32_16x16x32_bf16(a, b, c, 0, 0, 0);
}

// K=16 bf16 MFMA (PV step): A/B are 4 bf16 per lane, k = quad*4+j.
static __device__ __forceinline__ f32x4 mfma16k16(bf16x4 a, bf16x4 b, f32x4 c) {
#if __has_builtin(__builtin_amdgcn_mfma_f32_16x16x16bf16_1k)
  typedef short s4 __attribute__((ext_vector_type(4)));
  union U { bf16x4 h; s4 s; };
  U ua, ub; ua.h = a; ub.h = b;
  return __builtin_amdgcn_mfma_f32_16x16x16bf16_1k(ua.s, ub.s, c, 0, 0, 0);
#elif __has_builtin(__builtin_amdgcn_mfma_f32_16x16x16_bf16)
  return __builtin_amdgcn_mfma_f32_16x16x16_bf16(a, b, c, 0, 0, 0);
#else
  f32x4 d;
  asm volatile("v_mfma_f32_16x16x16_bf16 %0, %1, %2, %3"
               : "=v"(d) : "v"(a), "v"(b), "v"(c));
  return d;
#endif
}

#if __has_builtin(__builtin_amdgcn_exp2f)
#define EXP2F(x) __builtin_amdgcn_exp2f(x)
#else
#define EXP2F(x) exp2f(x)
#endif

static __device__ __forceinline__ void gld16(const bf16_t* g, bf16_t* l) {
  __builtin_amdgcn_global_load_lds(
      (const __attribute__((address_space(1))) void*)g,
      (__attribute__((address_space(3))) void*)l,
      16, 0, 0);
}

// ---------------- f32 -> bf16 cast (5 tensors in one launch) ----------------
struct CastArgs {
  const float* s[5];
  bf16_t* d[5];
  int n[5];
};

__global__ __launch_bounds__(256) void cast5_kernel(CastArgs a) {
  const int t = blockIdx.y;
  const int i8 = (blockIdx.x * 256 + threadIdx.x) * 8;
  if (i8 >= a.n[t]) return;
  const float4* s = (const float4*)(a.s[t] + i8);
  float4 x = s[0], y = s[1];
  bf16x8 o = {(bf16_t)x.x, (bf16_t)x.y, (bf16_t)x.z, (bf16_t)x.w,
              (bf16_t)y.x, (bf16_t)y.y, (bf16_t)y.z, (bf16_t)y.w};
  *(bf16x8*)(a.d[t] + i8) = o;
}

// ---------------------------------------------------------------------------
// Tiled GEMM: C = A(MxK) * W(NxK)^T, 128x128 tile, BK=32 (m97 structure).
// STORE 2: f32 row-major -> C0.
// STORE 3: fused QKV epilogue (N=3072): cols [0,2048) -> C0 bf16 row-major;
//   [2048,2560) -> Ck bf16 row-major (N=512); [2560,3072) -> Cv transposed
//   (B,KV,DH,L) with bf16x4 packed stores along L.
// ---------------------------------------------------------------------------
template <int STORE>
__global__ __launch_bounds__(256) void gemm_tile(const bf16_t* __restrict__ A,
                                                 const bf16_t* __restrict__ W,
                                                 void* __restrict__ C0,
                                                 bf16_t* __restrict__ Ck,
                                                 bf16_t* __restrict__ Cv,
                                                 int M, int N, int K) {
  __shared__ __align__(16) bf16_t As[128 * 32];
  __shared__ __align__(16) bf16_t Bs[128 * 32];
  const int tid  = threadIdx.x;
  const int lane = tid & 63;
  const int wave = tid >> 6;
  const int l15  = lane & 15;
  const int quad = lane >> 4;
  const int m0 = blockIdx.y * 128;
  const int n0 = blockIdx.x * 128;

  const int srow = wave * 32 + (lane >> 2);
  const int scol = (lane & 3) * 8;
  const bf16_t* ag = A + (size_t)(m0 + srow) * K + scol;
  const bf16_t* wg = W + (size_t)(n0 + srow) * K + scol;
  bf16_t* al = As + wave * 1024;
  bf16_t* bl = Bs + wave * 1024;

  const int wm = (wave >> 1) * 64;
  const int wn = (wave & 1) * 64;

  f32x4 acc[4][4];
#pragma unroll
  for (int mi = 0; mi < 4; mi++)
#pragma unroll
    for (int ni = 0; ni < 4; ni++) acc[mi][ni] = {0.f, 0.f, 0.f, 0.f};

  for (int k0 = 0; k0 < K; k0 += 32) {
    __syncthreads();
    gld16(ag + k0, al);
    gld16(ag + k0 + (size_t)16 * K, al + 512);
    gld16(wg + k0, bl);
    gld16(wg + k0 + (size_t)16 * K, bl + 512);
    __syncthreads();
    bf16x8 af[4], bfr[4];
#pragma unroll
    for (int mi = 0; mi < 4; mi++)
      af[mi] = *(const bf16x8*)(As + (wm + mi * 16 + l15) * 32 + quad * 8);
#pragma unroll
    for (int ni = 0; ni < 4; ni++)
      bfr[ni] = *(const bf16x8*)(Bs + (wn + ni * 16 + l15) * 32 + quad * 8);
#pragma unroll
    for (int mi = 0; mi < 4; mi++)
#pragma unroll
      for (int ni = 0; ni < 4; ni++)
        acc[mi][ni] = mfma16(af[mi], bfr[ni], acc[mi][ni]);
  }

  if (STORE == 2) {
    float* C = (float*)C0;
#pragma unroll
    for (int mi = 0; mi < 4; mi++) {
      const int row = m0 + wm + mi * 16 + quad * 4;
#pragma unroll
      for (int ni = 0; ni < 4; ni++) {
        const int col = n0 + wn + ni * 16 + l15;
#pragma unroll
        for (int i = 0; i < 4; i++)
          C[(size_t)(row + i) * N + col] = acc[mi][ni][i];
      }
    }
  } else {  // STORE == 3
    if (n0 < 2048) {
      bf16_t* C = (bf16_t*)C0;
#pragma unroll
      for (int mi = 0; mi < 4; mi++) {
        const int row = m0 + wm + mi * 16 + quad * 4;
#pragma unroll
        for (int ni = 0; ni < 4; ni++) {
          const int col = n0 + wn + ni * 16 + l15;
#pragma unroll
          for (int i = 0; i < 4; i++)
            C[(size_t)(row + i) * 2048 + col] = (bf16_t)acc[mi][ni][i];
        }
      }
    } else if (n0 < 2560) {
#pragma unroll
      for (int mi = 0; mi < 4; mi++) {
        const int row = m0 + wm + mi * 16 + quad * 4;
#pragma unroll
        for (int ni = 0; ni < 4; ni++) {
          const int col = n0 - 2048 + wn + ni * 16 + l15;
#pragma unroll
          for (int i = 0; i < 4; i++)
            Ck[(size_t)(row + i) * 512 + col] = (bf16_t)acc[mi][ni][i];
        }
      }
    } else {
#pragma unroll
      for (int mi = 0; mi < 4; mi++) {
        const int row = m0 + wm + mi * 16 + quad * 4;
        const int b = row >> 11;
        const int l0 = row & (LL - 1);
#pragma unroll
        for (int ni = 0; ni < 4; ni++) {
          const int kvcol = n0 - 2560 + wn + ni * 16 + l15;
          const int kvh = kvcol >> 7, d = kvcol & 127;
          bf16x4 w4 = {(bf16_t)acc[mi][ni][0], (bf16_t)acc[mi][ni][1],
                       (bf16_t)acc[mi][ni][2], (bf16_t)acc[mi][ni][3]};
          *(bf16x4*)(Cv + ((size_t)(b * HKV + kvh) * DHD + d) * LL + l0) = w4;
        }
      }
    }
  }
}

// In-place RoPE on q,k + padding-bias fill. One thread per (b,l,head,dpair).
// Q additionally pre-scaled by QSC = 1/sqrt(DH)*log2(e) (flash uses exp2).
__global__ void rope_kernel(bf16_t* __restrict__ q, bf16_t* __restrict__ k,
                            const int* __restrict__ amask, float* __restrict__ bias) {
  const int nq = BB * LL * HQ * 64;
  const int nk = BB * LL * HKV * 64;
  int id = blockIdx.x * blockDim.x + threadIdx.x;
  if (id >= nq + nk) {
    int id2 = id - (nq + nk);
    if (id2 < BB * LL) bias[id2] = (amask[id2] == 0) ? MINV : 0.0f;
    return;
  }
  bf16_t* base;
  int heads, idx;
  float sc;
  if (id < nq) { base = q; heads = HQ; idx = id; sc = QSC; }
  else         { base = k; heads = HKV; idx = id - nq; sc = 1.0f; }
  int d = idx & 63; idx >>= 6;
  int hh = idx % heads;
  int bl = idx / heads;      // b*LL + l
  int l = bl & (LL - 1);
  bf16_t* p = base + ((size_t)bl * heads + hh) * DHD + d;
  float x1 = (float)p[0];
  float x2 = (float)p[64];
  // invf = 10000^(-d/64) = exp(-d * ln(10000)/64)
  float invf = __expf(-(float)d * 0.14391156862532788f);
  float fr = (float)l * invf;
  float s, c;
  __sincosf(fr, &s, &c);
  p[0]  = (bf16_t)((x1 * c - x2 * s) * sc);
  p[64] = (bf16_t)((x2 * c + x1 * s) * sc);
}

// ---------------------------------------------------------------------------
// Flash attention: double-buffered K/V LDS, reg-staged prefetch, 1 raw
// barrier per round (lgkmcnt-only drain), register-resident P, LDS bias.
// Block: 256 threads = 4 waves; tile pair {c, 31-c}; wave w owns rows
// {c*64+w*16, (31-c)*64+w*16}. KV round = 64 keys.
// Kbuf[key 0..63][d 0..127] bf16, row 256B, byte ^= (row&7)<<4 swizzle.
// Vbuf[d 0..127][key-col 0..63] bf16, row 128B, same swizzle, with column
// permutation so a b128 read at col kt2*32+quad*8 yields K=16 A-frags for
// kt=2*kt2, 2*kt2+1.
// Pipeline: ISSUE(r+2) at end of round r; ds_write at end of round r+1;
// compute r+2 after the barrier. vmcnt never force-drained in the loop.
// ---------------------------------------------------------------------------
__global__ __launch_bounds__(256, 2) void flash_attn2(const bf16_t* __restrict__ q,
                                                      const bf16_t* __restrict__ k,
                                                      const bf16_t* __restrict__ vt,
                                                      const float* __restrict__ bias,
                                                      bf16_t* __restrict__ o) {
  __shared__ __align__(16) bf16_t Kbuf[2][64 * 128];   // 2 x 16 KB swizzled
  __shared__ __align__(16) bf16_t Vbuf[2][128 * 64];   // 2 x 16 KB swizzled
  __shared__ __align__(16) float  Bb[2048];            // 8 KB bias row

  const int tid  = threadIdx.x;
  const int lane = tid & 63;
  const int wave = tid >> 6;
  const int l15  = lane & 15;
  const int quad = lane >> 4;

  // Pair complementary workloads on the same CU: blocks i and i+256 usually
  // co-reside (2 blocks/CU); map them to c and 15-c (49 rounds total, always).
  const int bi   = blockIdx.x;
  const int half = bi >> 8;
  const int jj   = bi & 255;
  const int cc   = jj >> 5;
  const int c    = half ? (15 - cc) : cc;          // 0..15 : tile pair {c,31-c}
  const int bh = jj & 31;
  const int b  = bh >> 4;
  const int h  = bh & 15;
  const int kv = h >> 2;

  const int q0[2] = { c * 64 + wave * 16, (31 - c) * 64 + wave * 16 };
  const int nrounds = 32 - c;                      // >= 17

  bf16x8 qf[2][4];
#pragma unroll
  for (int qt = 0; qt < 2; qt++) {
    const bf16_t* qb = q + ((size_t)(b * LL + q0[qt] + l15)) * (HQ * DHD) + h * DHD + quad * 8;
#pragma unroll
    for (int t = 0; t < 4; t++) qf[qt][t] = *(const bf16x8*)(qb + 32 * t);
  }

  f32x4 acc[8][2];
#pragma unroll
  for (int mt = 0; mt < 8; mt++)
#pragma unroll
    for (int qt = 0; qt < 2; qt++) acc[mt][qt] = {0.f, 0.f, 0.f, 0.f};
  float m_i[2] = {-1e30f, -1e30f};
  float l_i[2] = {0.f, 0.f};

  const bf16_t* kg_base = k + ((size_t)(b * LL)) * (HKV * DHD) + kv * DHD;
  const bf16_t* vg_base = vt + ((size_t)(b * HKV + kv) * DHD) * LL;
  const float*  bias_b  = bias + b * LL;

  // Bias row -> LDS (8 KB, once per block).
  {
    const float4* bs = (const float4*)bias_b;
    float4* bd = (float4*)Bb;
    bd[tid]       = bs[tid];
    bd[tid + 256] = bs[tid + 256];
  }

  const int krow = tid >> 4, kch = tid & 15;
  const int vrow = tid >> 3, vch = tid & 7;
  // V column permutation for the low half of a bf16x8 global chunk at vch:
  // keys 8*vch+m -> col c(k); high half lands at +8 elems (+16 bytes).
  const int vc0  = ((vch >> 2) << 5) + (((vch << 1) & 3) << 3) + (((vch >> 1) & 1) << 2);
  const int vblo = vc0 * 2;                 // byte offset in 128B row
  const int ksw  = (krow & 7) << 4;         // (row&7)<<4; p*16 keeps row&7
  const int vsw  = (vrow & 7) << 4;         // p*32 keeps row&7
  const int rsw  = (l15 & 7) << 4;          // read-side swizzle (row = *16+l15)

  const bf16_t* kg0 = kg_base + (size_t)krow * (HKV * DHD) + kch * 8;
  const bf16_t* vg0 = vg_base + (size_t)vrow * LL + vch * 8;

  bf16x8 kl[4], vl[4];
  auto ISSUE = [&](int j0) {
#pragma unroll
    for (int p = 0; p < 4; p++)
      kl[p] = *(const bf16x8*)(kg0 + (size_t)j0 * (HKV * DHD) + (size_t)p * 16 * (HKV * DHD));
#pragma unroll
    for (int p = 0; p < 4; p++)
      vl[p] = *(const bf16x8*)(vg0 + j0 + (size_t)p * 32 * LL);
  };
  auto STAGE = [&](int bsel) {
    char* kb = (char*)(&Kbuf[bsel][0]);
    char* vb = (char*)(&Vbuf[bsel][0]);
#pragma unroll
    for (int p = 0; p < 4; p++)
      *(bf16x8*)(kb + (size_t)(krow + p * 16) * 256 + ((kch * 16) ^ ksw)) = kl[p];
#pragma unroll
    for (int p = 0; p < 4; p++) {
      char* vbase = vb + (size_t)(vrow + p * 32) * 128;
      bf16x4 lo4 = __builtin_shufflevector(vl[p], vl[p], 0, 1, 2, 3);
      bf16x4 hi4 = __builtin_shufflevector(vl[p], vl[p], 4, 5, 6, 7);
      *(bf16x4*)(vbase + (vblo ^ vsw)) = lo4;
      *(bf16x4*)(vbase + ((vblo + 16) ^ vsw)) = hi4;
    }
  };

  // Prologue: round 0 staged into buf0; round 1 loads in flight.
  ISSUE(0);
  STAGE(0);
  ISSUE(64);
  asm volatile("s_waitcnt lgkmcnt(0)" ::: "memory");
  __builtin_amdgcn_s_barrier();
  __builtin_amdgcn_sched_barrier(0);

  int cur = 0;
  for (int r = 0; r < nrounds; r++) {
    const int j0 = r * 64;
    const bool act_a = (r <= c);
    const char* KbC = (const char*)(&Kbuf[cur][0]);
    const char* VbC = (const char*)(&Vbuf[cur][0]);

    // ---- QK^T (S^T): A = K row, B = Q^T; D row = key (quad*4+i), col = qrow.
    f32x4 s[2][4];
    __builtin_amdgcn_s_setprio(1);
#pragma unroll
    for (int kt = 0; kt < 4; kt++) {
      const char* kr = KbC + (size_t)(kt * 16 + l15) * 256;
      f32x4 s0 = {0.f, 0.f, 0.f, 0.f};
      f32x4 s1 = {0.f, 0.f, 0.f, 0.f};
#pragma unroll
      for (int t = 0; t < 4; t++) {
        bf16x8 kf = *(const bf16x8*)(kr + ((quad * 16 + t * 64) ^ rsw));
        if (act_a) s0 = mfma16(kf, qf[0][t], s0);
        s1 = mfma16(kf, qf[1][t], s1);
      }
      s[0][kt] = s0; s[1][kt] = s1;
    }
    __builtin_amdgcn_s_setprio(0);

    // ---- online softmax in log2 domain (Q pre-scaled by QSC). P stays in
    //      registers: lane's p4 per kt IS the K=16 B-frag for PV.
    bf16x4 pf[2][4];
#pragma unroll
    for (int qt = 0; qt < 2; qt++) {
      if (qt == 0 && !act_a) continue;
      const int qrow = q0[qt] + l15;
      const bool diag = (j0 + 63 > q0[qt]);    // mask iff max key > MIN row
      float mx = -1e30f;
#pragma unroll
      for (int kt = 0; kt < 4; kt++) {
        f32x4 sv = s[qt][kt];
        f32x4 bv = *(const f32x4*)(&Bb[j0 + kt * 16 + quad * 4]);
#pragma unroll
        for (int i = 0; i < 4; i++) {
          float x = sv[i] + bv[i];
          if (diag) {
            int key = j0 + kt * 16 + quad * 4 + i;
            if (key > qrow) x = MINV;
          }
          sv[i] = x;
          mx = fmaxf(mx, x);
        }
        s[qt][kt] = sv;
      }
      mx = fmaxf(mx, __shfl_xor(mx, 16));
      mx = fmaxf(mx, __shfl_xor(mx, 32));
      // defer-max (T13): skip rescale while max grows < 8 (p bounded by 256).
      if (!__all(mx <= m_i[qt] + 8.0f)) {
        const float mn = fmaxf(m_i[qt], mx);
        const float alpha = EXP2F(m_i[qt] - mn);
        m_i[qt] = mn;
        l_i[qt] *= alpha;
#pragma unroll
        for (int mt = 0; mt < 8; mt++) {
          acc[mt][qt][0] *= alpha; acc[mt][qt][1] *= alpha;
          acc[mt][qt][2] *= alpha; acc[mt][qt][3] *= alpha;
        }
      }
      const float mn = m_i[qt];
      float sum = 0.f;
#pragma unroll
      for (int kt = 0; kt < 4; kt++) {
        f32x4 sv = s[qt][kt];
        bf16x4 p4;
#pragma unroll
        for (int i = 0; i < 4; i++) {
          float p = EXP2F(sv[i] - mn);
          sum += p;
          p4[i] = (bf16_t)p;
        }
        pf[qt][kt] = p4;
      }
      sum += __shfl_xor(sum, 16);
      sum += __shfl_xor(sum, 32);
      l_i[qt] += sum;
    }

    // ---- PV with K=16 MFMA: A = V^T frag (k=quad*4+j via permuted cols),
    //      B = pf (lane-local). acc layout unchanged: row=d, col=qrow.
    __builtin_amdgcn_s_setprio(1);
#pragma unroll
    for (int mt = 0; mt < 8; mt++) {
      const char* vr = VbC + (size_t)(mt * 16 + l15) * 128;
      bf16x8 v01 = *(const bf16x8*)(vr + ((quad * 16) ^ rsw));
      bf16x8 v23 = *(const bf16x8*)(vr + ((64 + quad * 16) ^ rsw));
      bf16x4 va = __builtin_shufflevector(v01, v01, 0, 1, 2, 3);
      bf16x4 vb = __builtin_shufflevector(v01, v01, 4, 5, 6, 7);
      bf16x4 vc = __builtin_shufflevector(v23, v23, 0, 1, 2, 3);
      bf16x4 vd = __builtin_shufflevector(v23, v23, 4, 5, 6, 7);
      if (act_a) {
        acc[mt][0] = mfma16k16(va, pf[0][0], acc[mt][0]);
        acc[mt][0] = mfma16k16(vb, pf[0][1], acc[mt][0]);
        acc[mt][0] = mfma16k16(vc, pf[0][2], acc[mt][0]);
        acc[mt][0] = mfma16k16(vd, pf[0][3], acc[mt][0]);
      }
      acc[mt][1] = mfma16k16(va, pf[1][0], acc[mt][1]);
      acc[mt][1] = mfma16k16(vb, pf[1][1], acc[mt][1]);
      acc[mt][1] = mfma16k16(vc, pf[1][2], acc[mt][1]);
      acc[mt][1] = mfma16k16(vd, pf[1][3], acc[mt][1]);
    }
    __builtin_amdgcn_s_setprio(0);

    // ---- pipeline tail of round r: stage r+1 into buf^1, issue r+2.
    if (r + 1 < nrounds) {
      STAGE(cur ^ 1);                       // vmcnt waits via data deps only
      if (r + 2 < nrounds) ISSUE((r + 2) * 64);
      asm volatile("s_waitcnt lgkmcnt(0)" ::: "memory");
      __builtin_amdgcn_s_barrier();
      __builtin_amdgcn_sched_barrier(0);
      cur ^= 1;
    }
  }

#pragma unroll
  for (int qt = 0; qt < 2; qt++) {
    const float invl = 1.0f / l_i[qt];
    bf16_t* ob = o + ((size_t)(b * LL + q0[qt] + l15)) * (HQ * DHD) + h * DHD + quad * 4;
#pragma unroll
    for (int mt = 0; mt < 8; mt++) {
      f32x4 a = acc[mt][qt];
      bf16x4 w = {(bf16_t)(a[0] * invl), (bf16_t)(a[1] * invl),
                  (bf16_t)(a[2] * invl), (bf16_t)(a[3] * invl)};
      *(bf16x4*)(ob + mt * 16) = w;
    }
  }
}

extern "C" void kernel_launch(void* const* d_in, const int* in_sizes, int n_in,
                              void* d_out, int out_size, void* d_ws, size_t ws_size,
                              hipStream_t stream) {
  const float* hidden = (const float*)d_in[0];
  const int*   amask  = (const int*)d_in[1];
  const float* Wq     = (const float*)d_in[2];
  const float* Wk     = (const float*)d_in[3];
  const float* Wv     = (const float*)d_in[4];
  const float* Wo     = (const float*)d_in[5];
  float* out = (float*)d_out;

  const int M = BB * LL;           // 4096
  const size_t MB = 1u << 20;
  char* ws = (char*)d_ws;
  bf16_t* hid_b   = (bf16_t*)(ws);            // 16 MB  (B,L,D)
  bf16_t* q_ws    = (bf16_t*)(ws + 16 * MB);  // 16 MB
  bf16_t* attn_ws = (bf16_t*)(ws + 32 * MB);  // 16 MB
  bf16_t* k_ws    = (bf16_t*)(ws + 48 * MB);  //  4 MB
  bf16_t* vt_ws   = (bf16_t*)(ws + 52 * MB);  //  4 MB
  bf16_t* wqkv_b  = (bf16_t*)(ws + 56 * MB);  // 12 MB: Wq(8) + Wk(2) + Wv(2)
  bf16_t* wq_b    = wqkv_b;
  bf16_t* wk_b    = (bf16_t*)(ws + 64 * MB);
  bf16_t* wv_b    = (bf16_t*)(ws + 66 * MB);
  bf16_t* wo_b    = (bf16_t*)(ws + 68 * MB);  //  8 MB
  float*  bias_ws = (float*)(ws);             // 16 KB, aliases hid_b

  CastArgs ca;
  ca.s[0] = hidden; ca.d[0] = hid_b; ca.n[0] = BB * LL * DDIM;
  ca.s[1] = Wq;     ca.d[1] = wq_b;  ca.n[1] = HQ * DHD * DDIM;
  ca.s[2] = Wk;     ca.d[2] = wk_b;  ca.n[2] = HKV * DHD * DDIM;
  ca.s[3] = Wv;     ca.d[3] = wv_b;  ca.n[3] = HKV * DHD * DDIM;
  ca.s[4] = Wo;     ca.d[4] = wo_b;  ca.n[4] = DDIM * DDIM;
  {
    int maxn = BB * LL * DDIM;
    dim3 g((maxn / 8 + 255) / 256, 5);
    cast5_kernel<<<g, 256, 0, stream>>>(ca);
  }

  gemm_tile<3><<<dim3(3072 / 128, M / 128), 256, 0, stream>>>(
      hid_b, wqkv_b, q_ws, k_ws, vt_ws, M, 3072, DDIM);

  {
    int total = BB * LL * (HQ + HKV) * 64 + BB * LL;
    rope_kernel<<<(total + 255) / 256, 256, 0, stream>>>(q_ws, k_ws, amask, bias_ws);
  }

  flash_attn2<<<BB * HQ * 16, 256, 0, stream>>>(q_ws, k_ws, vt_ws, bias_ws, attn_ws);

  gemm_tile<2><<<dim3(DDIM / 128, M / 128), 256, 0, stream>>>(
      attn_ws, wo_b, (void*)out, nullptr, nullptr, M, DDIM, DDIM);
}

// Round 3
// 330.193 us; speedup vs baseline: 1.1377x; 1.1377x over previous
//
#include <hip/hip_runtime.h>
#include <cstdint>
#include <cmath>

// ---------------------------------------------------------------------------
// LlamaAttention round 10: occupancy, not pipelining.
//   B=2 L=2048 D=2048 H=16 KV=4 DH=128, causal + key-padding mask, RoPE.
// R9 POST-MORTEM: explicit dbuf+prefetch regressed 96->138us; WRITE_SIZE
//   +28MB = scratch spills (kl/vl live across compute + sched_barrier(0)
//   pinning, per guide m141/rule20). Explicit pipelining rejected.
// REAL limiter found: grid = 512 blocks = exactly 2 blocks/CU = 2 waves/SIMD
//   (19% occupancy). VGPR(128) allows 4/SIMD, LDS(32KB) allows 5 blocks —
//   the GRID caps occupancy. Barrier drain is naked latency with 1 other
//   wave/SIMD; m114 says cross-block overlap is what absorbs it (3+ blk/CU).
// R10: 1024 blocks, each a balanced 32-row tile pair {p, 63-p}: waves 0-1
//   own tile p (16 rows each), waves 2-3 own tile 63-p; K/V staging shared.
//   Per-wave state halves (acc 8x1, qf 4) -> VGPR drops; 4 blocks/CU.
//   Dispatch bonus: CU i hosts blocks {i,i+256,i+512,i+768} = same (b,h,kv)
//   (identical K/V stream, L2-hot), staging rounds {32,28,24,20} balanced.
//   R8 codegen kept verbatim otherwise: 2 syncthreads/round, swizzled K/V
//   LDS, register-resident P via K=16 PV MFMA, exp2 softmax, defer-max.
// MFMA layouts (learn_hip m89/m91): A[m=l15][k], B[k][n=l15],
//   C/D: col=l15, row=quad*4+reg (shape-determined).
// ---------------------------------------------------------------------------

typedef __bf16 bf16_t;
typedef __bf16 bf16x8 __attribute__((ext_vector_type(8)));
typedef __bf16 bf16x4 __attribute__((ext_vector_type(4)));
typedef float  f32x4  __attribute__((ext_vector_type(4)));

#define HQ   16
#define HKV  4
#define GQA  4
#define DHD  128
#define BB   2
#define LL   2048
#define DDIM 2048
#define MINV (-1e15f)
// 1/sqrt(128) * log2(e): folded into Q at RoPE time so softmax uses exp2.
#define QSC  0.12751744f

static __device__ __forceinline__ f32x4 mfma16(bf16x8 a, bf16x8 b, f32x4 c) {
  return __builtin_amdgcn_mfma_f32_16x16x32_bf16(a, b, c, 0, 0, 0);
}

// K=16 bf16 MFMA (PV step): A/B are 4 bf16 per lane, k = quad*4+j.
static __device__ __forceinline__ f32x4 mfma16k16(bf16x4 a, bf16x4 b, f32x4 c) {
#if __has_builtin(__builtin_amdgcn_mfma_f32_16x16x16bf16_1k)
  typedef short s4 __attribute__((ext_vector_type(4)));
  union U { bf16x4 h; s4 s; };
  U ua, ub; ua.h = a; ub.h = b;
  return __builtin_amdgcn_mfma_f32_16x16x16bf16_1k(ua.s, ub.s, c, 0, 0, 0);
#elif __has_builtin(__builtin_amdgcn_mfma_f32_16x16x16_bf16)
  return __builtin_amdgcn_mfma_f32_16x16x16_bf16(a, b, c, 0, 0, 0);
#else
  f32x4 d;
  asm volatile("v_mfma_f32_16x16x16_bf16 %0, %1, %2, %3"
               : "=v"(d) : "v"(a), "v"(b), "v"(c));
  return d;
#endif
}

#if __has_builtin(__builtin_amdgcn_exp2f)
#define EXP2F(x) __builtin_amdgcn_exp2f(x)
#else
#define EXP2F(x) exp2f(x)
#endif

static __device__ __forceinline__ void gld16(const bf16_t* g, bf16_t* l) {
  __builtin_amdgcn_global_load_lds(
      (const __attribute__((address_space(1))) void*)g,
      (__attribute__((address_space(3))) void*)l,
      16, 0, 0);
}

// ---------------- f32 -> bf16 cast (5 tensors in one launch) ----------------
struct CastArgs {
  const float* s[5];
  bf16_t* d[5];
  int n[5];
};

__global__ __launch_bounds__(256) void cast5_kernel(CastArgs a) {
  const int t = blockIdx.y;
  const int i8 = (blockIdx.x * 256 + threadIdx.x) * 8;
  if (i8 >= a.n[t]) return;
  const float4* s = (const float4*)(a.s[t] + i8);
  float4 x = s[0], y = s[1];
  bf16x8 o = {(bf16_t)x.x, (bf16_t)x.y, (bf16_t)x.z, (bf16_t)x.w,
              (bf16_t)y.x, (bf16_t)y.y, (bf16_t)y.z, (bf16_t)y.w};
  *(bf16x8*)(a.d[t] + i8) = o;
}

// ---------------------------------------------------------------------------
// Tiled GEMM: C = A(MxK) * W(NxK)^T, 128x128 tile, BK=32 (m97 structure).
// STORE 2: f32 row-major -> C0.
// STORE 3: fused QKV epilogue (N=3072): cols [0,2048) -> C0 bf16 row-major;
//   [2048,2560) -> Ck bf16 row-major (N=512); [2560,3072) -> Cv transposed
//   (B,KV,DH,L) with bf16x4 packed stores along L.
// ---------------------------------------------------------------------------
template <int STORE>
__global__ __launch_bounds__(256) void gemm_tile(const bf16_t* __restrict__ A,
                                                 const bf16_t* __restrict__ W,
                                                 void* __restrict__ C0,
                                                 bf16_t* __restrict__ Ck,
                                                 bf16_t* __restrict__ Cv,
                                                 int M, int N, int K) {
  __shared__ __align__(16) bf16_t As[128 * 32];
  __shared__ __align__(16) bf16_t Bs[128 * 32];
  const int tid  = threadIdx.x;
  const int lane = tid & 63;
  const int wave = tid >> 6;
  const int l15  = lane & 15;
  const int quad = lane >> 4;
  const int m0 = blockIdx.y * 128;
  const int n0 = blockIdx.x * 128;

  const int srow = wave * 32 + (lane >> 2);
  const int scol = (lane & 3) * 8;
  const bf16_t* ag = A + (size_t)(m0 + srow) * K + scol;
  const bf16_t* wg = W + (size_t)(n0 + srow) * K + scol;
  bf16_t* al = As + wave * 1024;
  bf16_t* bl = Bs + wave * 1024;

  const int wm = (wave >> 1) * 64;
  const int wn = (wave & 1) * 64;

  f32x4 acc[4][4];
#pragma unroll
  for (int mi = 0; mi < 4; mi++)
#pragma unroll
    for (int ni = 0; ni < 4; ni++) acc[mi][ni] = {0.f, 0.f, 0.f, 0.f};

  for (int k0 = 0; k0 < K; k0 += 32) {
    __syncthreads();
    gld16(ag + k0, al);
    gld16(ag + k0 + (size_t)16 * K, al + 512);
    gld16(wg + k0, bl);
    gld16(wg + k0 + (size_t)16 * K, bl + 512);
    __syncthreads();
    bf16x8 af[4], bfr[4];
#pragma unroll
    for (int mi = 0; mi < 4; mi++)
      af[mi] = *(const bf16x8*)(As + (wm + mi * 16 + l15) * 32 + quad * 8);
#pragma unroll
    for (int ni = 0; ni < 4; ni++)
      bfr[ni] = *(const bf16x8*)(Bs + (wn + ni * 16 + l15) * 32 + quad * 8);
#pragma unroll
    for (int mi = 0; mi < 4; mi++)
#pragma unroll
      for (int ni = 0; ni < 4; ni++)
        acc[mi][ni] = mfma16(af[mi], bfr[ni], acc[mi][ni]);
  }

  if (STORE == 2) {
    float* C = (float*)C0;
#pragma unroll
    for (int mi = 0; mi < 4; mi++) {
      const int row = m0 + wm + mi * 16 + quad * 4;
#pragma unroll
      for (int ni = 0; ni < 4; ni++) {
        const int col = n0 + wn + ni * 16 + l15;
#pragma unroll
        for (int i = 0; i < 4; i++)
          C[(size_t)(row + i) * N + col] = acc[mi][ni][i];
      }
    }
  } else {  // STORE == 3
    if (n0 < 2048) {
      bf16_t* C = (bf16_t*)C0;
#pragma unroll
      for (int mi = 0; mi < 4; mi++) {
        const int row = m0 + wm + mi * 16 + quad * 4;
#pragma unroll
        for (int ni = 0; ni < 4; ni++) {
          const int col = n0 + wn + ni * 16 + l15;
#pragma unroll
          for (int i = 0; i < 4; i++)
            C[(size_t)(row + i) * 2048 + col] = (bf16_t)acc[mi][ni][i];
        }
      }
    } else if (n0 < 2560) {
#pragma unroll
      for (int mi = 0; mi < 4; mi++) {
        const int row = m0 + wm + mi * 16 + quad * 4;
#pragma unroll
        for (int ni = 0; ni < 4; ni++) {
          const int col = n0 - 2048 + wn + ni * 16 + l15;
#pragma unroll
          for (int i = 0; i < 4; i++)
            Ck[(size_t)(row + i) * 512 + col] = (bf16_t)acc[mi][ni][i];
        }
      }
    } else {
#pragma unroll
      for (int mi = 0; mi < 4; mi++) {
        const int row = m0 + wm + mi * 16 + quad * 4;
        const int b = row >> 11;
        const int l0 = row & (LL - 1);
#pragma unroll
        for (int ni = 0; ni < 4; ni++) {
          const int kvcol = n0 - 2560 + wn + ni * 16 + l15;
          const int kvh = kvcol >> 7, d = kvcol & 127;
          bf16x4 w4 = {(bf16_t)acc[mi][ni][0], (bf16_t)acc[mi][ni][1],
                       (bf16_t)acc[mi][ni][2], (bf16_t)acc[mi][ni][3]};
          *(bf16x4*)(Cv + ((size_t)(b * HKV + kvh) * DHD + d) * LL + l0) = w4;
        }
      }
    }
  }
}

// In-place RoPE on q,k + padding-bias fill. One thread per (b,l,head,dpair).
// Q additionally pre-scaled by QSC = 1/sqrt(DH)*log2(e) (flash uses exp2).
__global__ void rope_kernel(bf16_t* __restrict__ q, bf16_t* __restrict__ k,
                            const int* __restrict__ amask, float* __restrict__ bias) {
  const int nq = BB * LL * HQ * 64;
  const int nk = BB * LL * HKV * 64;
  int id = blockIdx.x * blockDim.x + threadIdx.x;
  if (id >= nq + nk) {
    int id2 = id - (nq + nk);
    if (id2 < BB * LL) bias[id2] = (amask[id2] == 0) ? MINV : 0.0f;
    return;
  }
  bf16_t* base;
  int heads, idx;
  float sc;
  if (id < nq) { base = q; heads = HQ; idx = id; sc = QSC; }
  else         { base = k; heads = HKV; idx = id - nq; sc = 1.0f; }
  int d = idx & 63; idx >>= 6;
  int hh = idx % heads;
  int bl = idx / heads;      // b*LL + l
  int l = bl & (LL - 1);
  bf16_t* p = base + ((size_t)bl * heads + hh) * DHD + d;
  float x1 = (float)p[0];
  float x2 = (float)p[64];
  // invf = 10000^(-d/64) = exp(-d * ln(10000)/64)
  float invf = __expf(-(float)d * 0.14391156862532788f);
  float fr = (float)l * invf;
  float s, c;
  __sincosf(fr, &s, &c);
  p[0]  = (bf16_t)((x1 * c - x2 * s) * sc);
  p[64] = (bf16_t)((x2 * c + x1 * s) * sc);
}

// ---------------------------------------------------------------------------
// Flash attention: 1024 blocks x 256 threads; block = balanced 32-row tile
// pair {p, 63-p}. Waves 0,1 -> tile p rows (wave&1)*16..+15; waves 2,3 ->
// tile 63-p. KV round = 64 keys staged block-wide (2 syncthreads/round).
// Kbuf[key 0..63][d 0..127] bf16, row 256B, byte ^= (row&7)<<4 swizzle.
// Vbuf[d 0..127][key-col 0..63] bf16, row 128B, same swizzle, with column
// permutation so a b128 read at col kt2*32+quad*8 yields K=16 A-frags for
// kt=2*kt2, 2*kt2+1. P register-resident (S^T lane layout = K=16 B-frag).
// ---------------------------------------------------------------------------
__global__ __launch_bounds__(256, 2) void flash_attn2(const bf16_t* __restrict__ q,
                                                      const bf16_t* __restrict__ k,
                                                      const bf16_t* __restrict__ vt,
                                                      const float* __restrict__ bias,
                                                      bf16_t* __restrict__ o) {
  __shared__ __align__(16) bf16_t Kbuf[64 * 128];    // 16 KB swizzled
  __shared__ __align__(16) bf16_t Vbuf[128 * 64];    // 16 KB swizzled+permuted

  const int tid  = threadIdx.x;
  const int lane = tid & 63;
  const int wave = tid >> 6;
  const int l15  = lane & 15;
  const int quad = lane >> 4;

  // 1024 blocks: CU i hosts {i, i+256, i+512, i+768} (breadth-first dispatch)
  // -> same bh (shared K/V stream), pairs p = {pp, pp+8, pp+16, pp+24} with
  // staging rounds {32,28,24,20}-ish: balanced per CU.
  const int gi = blockIdx.x;
  const int g  = gi >> 8;                 // 0..3
  const int j  = gi & 255;
  const int p  = (j >> 5) + 8 * g;        // pair index 0..31
  const int bh = j & 31;
  const int b  = bh >> 4;
  const int h  = bh & 15;
  const int kv = h >> 2;

  const int tile = (wave < 2) ? p : (63 - p);    // 32-row tile index
  const int q0   = tile * 32 + (wave & 1) * 16;  // this wave's 16-row strip
  const int nrounds = 32 - (p >> 1);             // rounds for tile 63-p (17..32)

  bf16x8 qf[4];
  {
    const bf16_t* qb = q + ((size_t)(b * LL + q0 + l15)) * (HQ * DHD) + h * DHD + quad * 8;
#pragma unroll
    for (int t = 0; t < 4; t++) qf[t] = *(const bf16x8*)(qb + 32 * t);
  }

  f32x4 acc[8];
#pragma unroll
  for (int mt = 0; mt < 8; mt++) acc[mt] = {0.f, 0.f, 0.f, 0.f};
  float m_i = -1e30f;
  float l_i = 0.f;

  const bf16_t* kg_base = k + ((size_t)(b * LL)) * (HKV * DHD) + kv * DHD;
  const bf16_t* vg_base = vt + ((size_t)(b * HKV + kv) * DHD) * LL;
  const float*  bias_b  = bias + b * LL;

  const int krow = tid >> 4, kch = tid & 15;
  const int vrow = tid >> 3, vch = tid & 7;
  // V column permutation for the low half of a bf16x8 global chunk at vch:
  // keys 8*vch+m -> col c(k); high half lands at +8 elems (+16 bytes).
  const int vc0  = ((vch >> 2) << 5) + (((vch << 1) & 3) << 3) + (((vch >> 1) & 1) << 2);
  const int vblo = vc0 * 2;                 // byte offset in 128B row
  const int ksw  = (krow & 7) << 4;         // (row&7)<<4; p*16 keeps row&7
  const int vsw  = (vrow & 7) << 4;         // p*32 keeps row&7
  const int rsw  = (l15 & 7) << 4;          // read-side swizzle (row = *16+l15)

  for (int r = 0; r < nrounds; r++) {
    const int j0 = r * 64;
    {
      const bf16_t* kg = kg_base + (size_t)(j0 + krow) * (HKV * DHD) + kch * 8;
      const bf16_t* vg = vg_base + (size_t)vrow * LL + j0 + vch * 8;
      bf16x8 kl[4], vl[4];
#pragma unroll
      for (int pp = 0; pp < 4; pp++) kl[pp] = *(const bf16x8*)(kg + (size_t)pp * 16 * (HKV * DHD));
#pragma unroll
      for (int pp = 0; pp < 4; pp++) vl[pp] = *(const bf16x8*)(vg + (size_t)pp * 32 * LL);
      __syncthreads();
#pragma unroll
      for (int pp = 0; pp < 4; pp++)
        *(bf16x8*)((char*)Kbuf + (size_t)(krow + pp * 16) * 256 + ((kch * 16) ^ ksw)) = kl[pp];
#pragma unroll
      for (int pp = 0; pp < 4; pp++) {
        char* vbase = (char*)Vbuf + (size_t)(vrow + pp * 32) * 128;
        bf16x4 lo4 = __builtin_shufflevector(vl[pp], vl[pp], 0, 1, 2, 3);
        bf16x4 hi4 = __builtin_shufflevector(vl[pp], vl[pp], 4, 5, 6, 7);
        *(bf16x4*)(vbase + (vblo ^ vsw)) = lo4;
        *(bf16x4*)(vbase + ((vblo + 16) ^ vsw)) = hi4;
      }
      __syncthreads();
    }

    const bool act = (j0 <= q0 + 15);   // wave-uniform: this strip has keys here
    if (act) {
      // ---- QK^T (S^T): A = K row, B = Q^T; D row = key (quad*4+i), col = qrow.
      f32x4 s[4];
#pragma unroll
      for (int kt = 0; kt < 4; kt++) {
        const char* kr = (const char*)Kbuf + (size_t)(kt * 16 + l15) * 256;
        f32x4 s0 = {0.f, 0.f, 0.f, 0.f};
#pragma unroll
        for (int t = 0; t < 4; t++) {
          bf16x8 kf = *(const bf16x8*)(kr + ((quad * 16 + t * 64) ^ rsw));
          s0 = mfma16(kf, qf[t], s0);
        }
        s[kt] = s0;
      }

      // ---- online softmax in log2 domain (Q pre-scaled by QSC). P stays in
      //      registers: lane's p4 per kt IS the K=16 B-frag for PV.
      const int qrow = q0 + l15;
      const bool diag = (j0 + 63 > q0);      // mask iff max key > min row
      float mx = -1e30f;
#pragma unroll
      for (int kt = 0; kt < 4; kt++) {
        f32x4 sv = s[kt];
        f32x4 bv = *(const f32x4*)(bias_b + j0 + kt * 16 + quad * 4);
#pragma unroll
        for (int i = 0; i < 4; i++) {
          float x = sv[i] + bv[i];
          if (diag) {
            int key = j0 + kt * 16 + quad * 4 + i;
            if (key > qrow) x = MINV;
          }
          sv[i] = x;
          mx = fmaxf(mx, x);
        }
        s[kt] = sv;
      }
      mx = fmaxf(mx, __shfl_xor(mx, 16));
      mx = fmaxf(mx, __shfl_xor(mx, 32));
      // defer-max (T13): skip rescale while max grows < 8 (p bounded by 256).
      if (!__all(mx <= m_i + 8.0f)) {
        const float mn = fmaxf(m_i, mx);
        const float alpha = EXP2F(m_i - mn);
        m_i = mn;
        l_i *= alpha;
#pragma unroll
        for (int mt = 0; mt < 8; mt++) {
          acc[mt][0] *= alpha; acc[mt][1] *= alpha;
          acc[mt][2] *= alpha; acc[mt][3] *= alpha;
        }
      }
      const float mn = m_i;
      float sum = 0.f;
      bf16x4 pf[4];
#pragma unroll
      for (int kt = 0; kt < 4; kt++) {
        f32x4 sv = s[kt];
        bf16x4 p4;
#pragma unroll
        for (int i = 0; i < 4; i++) {
          float pe = EXP2F(sv[i] - mn);
          sum += pe;
          p4[i] = (bf16_t)pe;
        }
        pf[kt] = p4;
      }
      sum += __shfl_xor(sum, 16);
      sum += __shfl_xor(sum, 32);
      l_i += sum;

      // ---- PV with K=16 MFMA: A = V^T frag (k=quad*4+j via permuted cols),
      //      B = pf (lane-local). acc layout: row=d (mt*16+quad*4+i), col=qrow.
#pragma unroll
      for (int mt = 0; mt < 8; mt++) {
        const char* vr = (const char*)Vbuf + (size_t)(mt * 16 + l15) * 128;
        bf16x8 v01 = *(const bf16x8*)(vr + ((quad * 16) ^ rsw));
        bf16x8 v23 = *(const bf16x8*)(vr + ((64 + quad * 16) ^ rsw));
        bf16x4 va = __builtin_shufflevector(v01, v01, 0, 1, 2, 3);
        bf16x4 vb = __builtin_shufflevector(v01, v01, 4, 5, 6, 7);
        bf16x4 vc = __builtin_shufflevector(v23, v23, 0, 1, 2, 3);
        bf16x4 vd = __builtin_shufflevector(v23, v23, 4, 5, 6, 7);
        acc[mt] = mfma16k16(va, pf[0], acc[mt]);
        acc[mt] = mfma16k16(vb, pf[1], acc[mt]);
        acc[mt] = mfma16k16(vc, pf[2], acc[mt]);
        acc[mt] = mfma16k16(vd, pf[3], acc[mt]);
      }
    }
  }

  {
    const float invl = 1.0f / l_i;
    bf16_t* ob = o + ((size_t)(b * LL + q0 + l15)) * (HQ * DHD) + h * DHD + quad * 4;
#pragma unroll
    for (int mt = 0; mt < 8; mt++) {
      f32x4 a = acc[mt];
      bf16x4 w = {(bf16_t)(a[0] * invl), (bf16_t)(a[1] * invl),
                  (bf16_t)(a[2] * invl), (bf16_t)(a[3] * invl)};
      *(bf16x4*)(ob + mt * 16) = w;
    }
  }
}

extern "C" void kernel_launch(void* const* d_in, const int* in_sizes, int n_in,
                              void* d_out, int out_size, void* d_ws, size_t ws_size,
                              hipStream_t stream) {
  const float* hidden = (const float*)d_in[0];
  const int*   amask  = (const int*)d_in[1];
  const float* Wq     = (const float*)d_in[2];
  const float* Wk     = (const float*)d_in[3];
  const float* Wv     = (const float*)d_in[4];
  const float* Wo     = (const float*)d_in[5];
  float* out = (float*)d_out;

  const int M = BB * LL;           // 4096
  const size_t MB = 1u << 20;
  char* ws = (char*)d_ws;
  bf16_t* hid_b   = (bf16_t*)(ws);            // 16 MB  (B,L,D)
  bf16_t* q_ws    = (bf16_t*)(ws + 16 * MB);  // 16 MB
  bf16_t* attn_ws = (bf16_t*)(ws + 32 * MB);  // 16 MB
  bf16_t* k_ws    = (bf16_t*)(ws + 48 * MB);  //  4 MB
  bf16_t* vt_ws   = (bf16_t*)(ws + 52 * MB);  //  4 MB
  bf16_t* wqkv_b  = (bf16_t*)(ws + 56 * MB);  // 12 MB: Wq(8) + Wk(2) + Wv(2)
  bf16_t* wq_b    = wqkv_b;
  bf16_t* wk_b    = (bf16_t*)(ws + 64 * MB);
  bf16_t* wv_b    = (bf16_t*)(ws + 66 * MB);
  bf16_t* wo_b    = (bf16_t*)(ws + 68 * MB);  //  8 MB
  float*  bias_ws = (float*)(ws);             // 16 KB, aliases hid_b

  CastArgs ca;
  ca.s[0] = hidden; ca.d[0] = hid_b; ca.n[0] = BB * LL * DDIM;
  ca.s[1] = Wq;     ca.d[1] = wq_b;  ca.n[1] = HQ * DHD * DDIM;
  ca.s[2] = Wk;     ca.d[2] = wk_b;  ca.n[2] = HKV * DHD * DDIM;
  ca.s[3] = Wv;     ca.d[3] = wv_b;  ca.n[3] = HKV * DHD * DDIM;
  ca.s[4] = Wo;     ca.d[4] = wo_b;  ca.n[4] = DDIM * DDIM;
  {
    int maxn = BB * LL * DDIM;
    dim3 g((maxn / 8 + 255) / 256, 5);
    cast5_kernel<<<g, 256, 0, stream>>>(ca);
  }

  gemm_tile<3><<<dim3(3072 / 128, M / 128), 256, 0, stream>>>(
      hid_b, wqkv_b, q_ws, k_ws, vt_ws, M, 3072, DDIM);

  {
    int total = BB * LL * (HQ + HKV) * 64 + BB * LL;
    rope_kernel<<<(total + 255) / 256, 256, 0, stream>>>(q_ws, k_ws, amask, bias_ws);
  }

  flash_attn2<<<1024, 256, 0, stream>>>(q_ws, k_ws, vt_ws, bias_ws, attn_ws);

  gemm_tile<2><<<dim3(DDIM / 128, M / 128), 256, 0, stream>>>(
      attn_ws, wo_b, (void*)out, nullptr, nullptr, M, DDIM, DDIM);
}

// Round 4
// 319.896 us; speedup vs baseline: 1.1743x; 1.0322x over previous
//
#include <hip/hip_runtime.h>
#include <cstdint>
#include <cmath>

// ---------------------------------------------------------------------------
// LlamaAttention round 11: halve flash rounds, keep occupancy, hide latency.
//   B=2 L=2048 D=2048 H=16 KV=4 DH=128, causal + key-padding mask, RoPE.
// R10 POST-MORTEM: occupancy 19->35% but dur only -5%. R10 doubled block-
//   rounds (25088) => staging bytes + barriers doubled; every round still
//   exposes full load->vmcnt(0) drain at the first barrier.
// R11: 512 blocks x 512 threads (8 waves): block owns 128-row pair {c,31-c}
//   (waves 0-3 tile c, waves 4-7 tile 31-c) => block-rounds back to 12544,
//   occupancy stays 16 waves/CU (2 blocks x 8 waves).
//   + double-buffered K/V LDS, ONE __syncthreads per round (write-after-read
//     protected by buffer alternation + the single barrier).
//   + T14 issue-early: round r issues r+1 loads (16 VGPR) BEFORE compute, so
//     the barrier's vmcnt drain lands after ~600cy of compute.
//   + bias row staged once to LDS (8KB): compute phase has no global loads.
//   NO asm barriers / sched_barrier / setprio (R9 spill+pinning lesson).
// Kept: XOR-swizzled K/V LDS, register-resident P via K=16 PV MFMA, exp2
//   softmax (Q pre-scaled), defer-max, c/15-c block pairing (49 rounds/CU).
// MFMA layouts (learn_hip m89/m91): A[m=l15][k], B[k][n=l15],
//   C/D: col=l15, row=quad*4+reg (shape-determined).
// ---------------------------------------------------------------------------

typedef __bf16 bf16_t;
typedef __bf16 bf16x8 __attribute__((ext_vector_type(8)));
typedef __bf16 bf16x4 __attribute__((ext_vector_type(4)));
typedef float  f32x4  __attribute__((ext_vector_type(4)));

#define HQ   16
#define HKV  4
#define GQA  4
#define DHD  128
#define BB   2
#define LL   2048
#define DDIM 2048
#define MINV (-1e15f)
// 1/sqrt(128) * log2(e): folded into Q at RoPE time so softmax uses exp2.
#define QSC  0.12751744f

static __device__ __forceinline__ f32x4 mfma16(bf16x8 a, bf16x8 b, f32x4 c) {
  return __builtin_amdgcn_mfma_f32_16x16x32_bf16(a, b, c, 0, 0, 0);
}

// K=16 bf16 MFMA (PV step): A/B are 4 bf16 per lane, k = quad*4+j.
static __device__ __forceinline__ f32x4 mfma16k16(bf16x4 a, bf16x4 b, f32x4 c) {
#if __has_builtin(__builtin_amdgcn_mfma_f32_16x16x16bf16_1k)
  typedef short s4 __attribute__((ext_vector_type(4)));
  union U { bf16x4 h; s4 s; };
  U ua, ub; ua.h = a; ub.h = b;
  return __builtin_amdgcn_mfma_f32_16x16x16bf16_1k(ua.s, ub.s, c, 0, 0, 0);
#elif __has_builtin(__builtin_amdgcn_mfma_f32_16x16x16_bf16)
  return __builtin_amdgcn_mfma_f32_16x16x16_bf16(a, b, c, 0, 0, 0);
#else
  f32x4 d;
  asm volatile("v_mfma_f32_16x16x16_bf16 %0, %1, %2, %3"
               : "=v"(d) : "v"(a), "v"(b), "v"(c));
  return d;
#endif
}

#if __has_builtin(__builtin_amdgcn_exp2f)
#define EXP2F(x) __builtin_amdgcn_exp2f(x)
#else
#define EXP2F(x) exp2f(x)
#endif

static __device__ __forceinline__ void gld16(const bf16_t* g, bf16_t* l) {
  __builtin_amdgcn_global_load_lds(
      (const __attribute__((address_space(1))) void*)g,
      (__attribute__((address_space(3))) void*)l,
      16, 0, 0);
}

// ---------------- f32 -> bf16 cast (5 tensors in one launch) ----------------
struct CastArgs {
  const float* s[5];
  bf16_t* d[5];
  int n[5];
};

__global__ __launch_bounds__(256) void cast5_kernel(CastArgs a) {
  const int t = blockIdx.y;
  const int i8 = (blockIdx.x * 256 + threadIdx.x) * 8;
  if (i8 >= a.n[t]) return;
  const float4* s = (const float4*)(a.s[t] + i8);
  float4 x = s[0], y = s[1];
  bf16x8 o = {(bf16_t)x.x, (bf16_t)x.y, (bf16_t)x.z, (bf16_t)x.w,
              (bf16_t)y.x, (bf16_t)y.y, (bf16_t)y.z, (bf16_t)y.w};
  *(bf16x8*)(a.d[t] + i8) = o;
}

// ---------------------------------------------------------------------------
// Tiled GEMM: C = A(MxK) * W(NxK)^T, 128x128 tile, BK=32 (m97 structure).
// STORE 2: f32 row-major -> C0.
// STORE 3: fused QKV epilogue (N=3072): cols [0,2048) -> C0 bf16 row-major;
//   [2048,2560) -> Ck bf16 row-major (N=512); [2560,3072) -> Cv transposed
//   (B,KV,DH,L) with bf16x4 packed stores along L.
// ---------------------------------------------------------------------------
template <int STORE>
__global__ __launch_bounds__(256) void gemm_tile(const bf16_t* __restrict__ A,
                                                 const bf16_t* __restrict__ W,
                                                 void* __restrict__ C0,
                                                 bf16_t* __restrict__ Ck,
                                                 bf16_t* __restrict__ Cv,
                                                 int M, int N, int K) {
  __shared__ __align__(16) bf16_t As[128 * 32];
  __shared__ __align__(16) bf16_t Bs[128 * 32];
  const int tid  = threadIdx.x;
  const int lane = tid & 63;
  const int wave = tid >> 6;
  const int l15  = lane & 15;
  const int quad = lane >> 4;
  const int m0 = blockIdx.y * 128;
  const int n0 = blockIdx.x * 128;

  const int srow = wave * 32 + (lane >> 2);
  const int scol = (lane & 3) * 8;
  const bf16_t* ag = A + (size_t)(m0 + srow) * K + scol;
  const bf16_t* wg = W + (size_t)(n0 + srow) * K + scol;
  bf16_t* al = As + wave * 1024;
  bf16_t* bl = Bs + wave * 1024;

  const int wm = (wave >> 1) * 64;
  const int wn = (wave & 1) * 64;

  f32x4 acc[4][4];
#pragma unroll
  for (int mi = 0; mi < 4; mi++)
#pragma unroll
    for (int ni = 0; ni < 4; ni++) acc[mi][ni] = {0.f, 0.f, 0.f, 0.f};

  for (int k0 = 0; k0 < K; k0 += 32) {
    __syncthreads();
    gld16(ag + k0, al);
    gld16(ag + k0 + (size_t)16 * K, al + 512);
    gld16(wg + k0, bl);
    gld16(wg + k0 + (size_t)16 * K, bl + 512);
    __syncthreads();
    bf16x8 af[4], bfr[4];
#pragma unroll
    for (int mi = 0; mi < 4; mi++)
      af[mi] = *(const bf16x8*)(As + (wm + mi * 16 + l15) * 32 + quad * 8);
#pragma unroll
    for (int ni = 0; ni < 4; ni++)
      bfr[ni] = *(const bf16x8*)(Bs + (wn + ni * 16 + l15) * 32 + quad * 8);
#pragma unroll
    for (int mi = 0; mi < 4; mi++)
#pragma unroll
      for (int ni = 0; ni < 4; ni++)
        acc[mi][ni] = mfma16(af[mi], bfr[ni], acc[mi][ni]);
  }

  if (STORE == 2) {
    float* C = (float*)C0;
#pragma unroll
    for (int mi = 0; mi < 4; mi++) {
      const int row = m0 + wm + mi * 16 + quad * 4;
#pragma unroll
      for (int ni = 0; ni < 4; ni++) {
        const int col = n0 + wn + ni * 16 + l15;
#pragma unroll
        for (int i = 0; i < 4; i++)
          C[(size_t)(row + i) * N + col] = acc[mi][ni][i];
      }
    }
  } else {  // STORE == 3
    if (n0 < 2048) {
      bf16_t* C = (bf16_t*)C0;
#pragma unroll
      for (int mi = 0; mi < 4; mi++) {
        const int row = m0 + wm + mi * 16 + quad * 4;
#pragma unroll
        for (int ni = 0; ni < 4; ni++) {
          const int col = n0 + wn + ni * 16 + l15;
#pragma unroll
          for (int i = 0; i < 4; i++)
            C[(size_t)(row + i) * 2048 + col] = (bf16_t)acc[mi][ni][i];
        }
      }
    } else if (n0 < 2560) {
#pragma unroll
      for (int mi = 0; mi < 4; mi++) {
        const int row = m0 + wm + mi * 16 + quad * 4;
#pragma unroll
        for (int ni = 0; ni < 4; ni++) {
          const int col = n0 - 2048 + wn + ni * 16 + l15;
#pragma unroll
          for (int i = 0; i < 4; i++)
            Ck[(size_t)(row + i) * 512 + col] = (bf16_t)acc[mi][ni][i];
        }
      }
    } else {
#pragma unroll
      for (int mi = 0; mi < 4; mi++) {
        const int row = m0 + wm + mi * 16 + quad * 4;
        const int b = row >> 11;
        const int l0 = row & (LL - 1);
#pragma unroll
        for (int ni = 0; ni < 4; ni++) {
          const int kvcol = n0 - 2560 + wn + ni * 16 + l15;
          const int kvh = kvcol >> 7, d = kvcol & 127;
          bf16x4 w4 = {(bf16_t)acc[mi][ni][0], (bf16_t)acc[mi][ni][1],
                       (bf16_t)acc[mi][ni][2], (bf16_t)acc[mi][ni][3]};
          *(bf16x4*)(Cv + ((size_t)(b * HKV + kvh) * DHD + d) * LL + l0) = w4;
        }
      }
    }
  }
}

// In-place RoPE on q,k + padding-bias fill. One thread per (b,l,head,dpair).
// Q additionally pre-scaled by QSC = 1/sqrt(DH)*log2(e) (flash uses exp2).
__global__ void rope_kernel(bf16_t* __restrict__ q, bf16_t* __restrict__ k,
                            const int* __restrict__ amask, float* __restrict__ bias) {
  const int nq = BB * LL * HQ * 64;
  const int nk = BB * LL * HKV * 64;
  int id = blockIdx.x * blockDim.x + threadIdx.x;
  if (id >= nq + nk) {
    int id2 = id - (nq + nk);
    if (id2 < BB * LL) bias[id2] = (amask[id2] == 0) ? MINV : 0.0f;
    return;
  }
  bf16_t* base;
  int heads, idx;
  float sc;
  if (id < nq) { base = q; heads = HQ; idx = id; sc = QSC; }
  else         { base = k; heads = HKV; idx = id - nq; sc = 1.0f; }
  int d = idx & 63; idx >>= 6;
  int hh = idx % heads;
  int bl = idx / heads;      // b*LL + l
  int l = bl & (LL - 1);
  bf16_t* p = base + ((size_t)bl * heads + hh) * DHD + d;
  float x1 = (float)p[0];
  float x2 = (float)p[64];
  // invf = 10000^(-d/64) = exp(-d * ln(10000)/64)
  float invf = __expf(-(float)d * 0.14391156862532788f);
  float fr = (float)l * invf;
  float s, c;
  __sincosf(fr, &s, &c);
  p[0]  = (bf16_t)((x1 * c - x2 * s) * sc);
  p[64] = (bf16_t)((x2 * c + x1 * s) * sc);
}

// ---------------------------------------------------------------------------
// Flash attention: 512 blocks x 512 threads (8 waves). Block owns 128-row
// tile pair {c, 31-c}: waves 0-3 -> tile c (16-row strips), waves 4-7 ->
// tile 31-c. KV round = 64 keys, double-buffered LDS, 1 barrier/round.
// Kbuf[key 0..63][d 0..127] bf16, row 256B, byte ^= (row&7)<<4 swizzle.
// Vbuf[d 0..127][key-col 0..63] bf16, row 128B, same swizzle, with column
// permutation so a b128 read at col kt2*32+quad*8 yields K=16 A-frags for
// kt=2*kt2, 2*kt2+1. P register-resident (S^T lane layout = K=16 B-frag).
// Round r: issue loads r+1 -> compute buf[cur] -> write buf[cur^1] -> sync.
// ---------------------------------------------------------------------------
__global__ __launch_bounds__(512, 4) void flash_attn2(const bf16_t* __restrict__ q,
                                                      const bf16_t* __restrict__ k,
                                                      const bf16_t* __restrict__ vt,
                                                      const float* __restrict__ bias,
                                                      bf16_t* __restrict__ o) {
  __shared__ __align__(16) bf16_t Kbuf[2][64 * 128];   // 2 x 16 KB swizzled
  __shared__ __align__(16) bf16_t Vbuf[2][128 * 64];   // 2 x 16 KB swizzled
  __shared__ __align__(16) float  Bb[2048];            // 8 KB bias row

  const int tid  = threadIdx.x;
  const int lane = tid & 63;
  const int wave = tid >> 6;
  const int l15  = lane & 15;
  const int quad = lane >> 4;

  // 512 blocks, 2/CU: co-resident pair {i, i+256} -> c and 15-c
  // (rounds (32-c) + (17+c) = 49, balanced per CU).
  const int bi   = blockIdx.x;
  const int half = bi >> 8;
  const int jj   = bi & 255;
  const int cc   = jj >> 5;
  const int c    = half ? (15 - cc) : cc;          // 0..15
  const int bh = jj & 31;
  const int b  = bh >> 4;
  const int h  = bh & 15;
  const int kv = h >> 2;

  const int tile = (wave < 4) ? c : (31 - c);      // 64-row tile index
  const int q0   = tile * 64 + (wave & 3) * 16;    // this wave's 16-row strip
  const int nrounds = 32 - c;                      // 17..32

  bf16x8 qf[4];
  {
    const bf16_t* qb = q + ((size_t)(b * LL + q0 + l15)) * (HQ * DHD) + h * DHD + quad * 8;
#pragma unroll
    for (int t = 0; t < 4; t++) qf[t] = *(const bf16x8*)(qb + 32 * t);
  }

  f32x4 acc[8];
#pragma unroll
  for (int mt = 0; mt < 8; mt++) acc[mt] = {0.f, 0.f, 0.f, 0.f};
  float m_i = -1e30f;
  float l_i = 0.f;

  const bf16_t* kg_base = k + ((size_t)(b * LL)) * (HKV * DHD) + kv * DHD;
  const bf16_t* vg_base = vt + ((size_t)(b * HKV + kv) * DHD) * LL;
  const float*  bias_b  = bias + b * LL;

  // Bias row -> LDS (8 KB once; 512 float4 = 2048 floats).
  ((float4*)Bb)[tid] = ((const float4*)bias_b)[tid];

  // Staging split across 512 threads: K 64x128 (2 chunks of 32 rows),
  // V^T 128x64 (2 chunks of 64 d-rows).
  const int krow = tid >> 4, kch = tid & 15;       // krow 0..31
  const int vrow = tid >> 3, vch = tid & 7;        // vrow 0..63
  // V column permutation for the low half of a bf16x8 global chunk at vch:
  // keys 8*vch+m -> col c(k); high half lands at +8 elems (+16 bytes).
  const int vc0  = ((vch >> 2) << 5) + (((vch << 1) & 3) << 3) + (((vch >> 1) & 1) << 2);
  const int vblo = vc0 * 2;                 // byte offset in 128B row
  const int ksw  = (krow & 7) << 4;         // row&7 preserved by +32 chunks
  const int vsw  = (vrow & 7) << 4;         // row&7 preserved by +64 chunks
  const int rsw  = (l15 & 7) << 4;          // read-side swizzle (row = *16+l15)

  const bf16_t* kg0 = kg_base + (size_t)krow * (HKV * DHD) + kch * 8;
  const bf16_t* vg0 = vg_base + (size_t)vrow * LL + vch * 8;

  bf16x8 kl[2], vl[2];
  auto ISSUE = [&](int j0) {
#pragma unroll
    for (int p = 0; p < 2; p++)
      kl[p] = *(const bf16x8*)(kg0 + (size_t)(j0 + p * 32) * (HKV * DHD));
#pragma unroll
    for (int p = 0; p < 2; p++)
      vl[p] = *(const bf16x8*)(vg0 + j0 + (size_t)p * 64 * LL);
  };
  auto STAGE = [&](int bsel) {
    char* kb = (char*)(&Kbuf[bsel][0]);
    char* vb = (char*)(&Vbuf[bsel][0]);
#pragma unroll
    for (int p = 0; p < 2; p++)
      *(bf16x8*)(kb + (size_t)(krow + p * 32) * 256 + ((kch * 16) ^ ksw)) = kl[p];
#pragma unroll
    for (int p = 0; p < 2; p++) {
      char* vbase = vb + (size_t)(vrow + p * 64) * 128;
      bf16x4 lo4 = __builtin_shufflevector(vl[p], vl[p], 0, 1, 2, 3);
      bf16x4 hi4 = __builtin_shufflevector(vl[p], vl[p], 4, 5, 6, 7);
      *(bf16x4*)(vbase + (vblo ^ vsw)) = lo4;
      *(bf16x4*)(vbase + ((vblo + 16) ^ vsw)) = hi4;
    }
  };

  // Prologue: stage round 0 into buf0.
  ISSUE(0);
  STAGE(0);
  __syncthreads();

  int cur = 0;
  for (int r = 0; r < nrounds; r++) {
    const int j0 = r * 64;
    const bool last = (r + 1 >= nrounds);
    if (!last) ISSUE(j0 + 64);   // issue-early: lands during compute (T14)

    const bool act = (j0 <= q0 + 15);   // wave-uniform
    if (act) {
      const char* KbC = (const char*)(&Kbuf[cur][0]);
      const char* VbC = (const char*)(&Vbuf[cur][0]);

      // ---- QK^T (S^T): A = K row, B = Q^T; D row = key (quad*4+i), col = qrow.
      f32x4 s[4];
#pragma unroll
      for (int kt = 0; kt < 4; kt++) {
        const char* kr = KbC + (size_t)(kt * 16 + l15) * 256;
        f32x4 s0 = {0.f, 0.f, 0.f, 0.f};
#pragma unroll
        for (int t = 0; t < 4; t++) {
          bf16x8 kf = *(const bf16x8*)(kr + ((quad * 16 + t * 64) ^ rsw));
          s0 = mfma16(kf, qf[t], s0);
        }
        s[kt] = s0;
      }

      // ---- online softmax in log2 domain (Q pre-scaled by QSC). P stays in
      //      registers: lane's p4 per kt IS the K=16 B-frag for PV.
      const int qrow = q0 + l15;
      const bool diag = (j0 + 63 > q0);      // mask iff max key > min row
      float mx = -1e30f;
#pragma unroll
      for (int kt = 0; kt < 4; kt++) {
        f32x4 sv = s[kt];
        f32x4 bv = *(const f32x4*)(&Bb[j0 + kt * 16 + quad * 4]);
#pragma unroll
        for (int i = 0; i < 4; i++) {
          float x = sv[i] + bv[i];
          if (diag) {
            int key = j0 + kt * 16 + quad * 4 + i;
            if (key > qrow) x = MINV;
          }
          sv[i] = x;
          mx = fmaxf(mx, x);
        }
        s[kt] = sv;
      }
      mx = fmaxf(mx, __shfl_xor(mx, 16));
      mx = fmaxf(mx, __shfl_xor(mx, 32));
      // defer-max (T13): skip rescale while max grows < 8 (p bounded by 256).
      if (!__all(mx <= m_i + 8.0f)) {
        const float mn = fmaxf(m_i, mx);
        const float alpha = EXP2F(m_i - mn);
        m_i = mn;
        l_i *= alpha;
#pragma unroll
        for (int mt = 0; mt < 8; mt++) {
          acc[mt][0] *= alpha; acc[mt][1] *= alpha;
          acc[mt][2] *= alpha; acc[mt][3] *= alpha;
        }
      }
      const float mn = m_i;
      float sum = 0.f;
      bf16x4 pf[4];
#pragma unroll
      for (int kt = 0; kt < 4; kt++) {
        f32x4 sv = s[kt];
        bf16x4 p4;
#pragma unroll
        for (int i = 0; i < 4; i++) {
          float pe = EXP2F(sv[i] - mn);
          sum += pe;
          p4[i] = (bf16_t)pe;
        }
        pf[kt] = p4;
      }
      sum += __shfl_xor(sum, 16);
      sum += __shfl_xor(sum, 32);
      l_i += sum;

      // ---- PV with K=16 MFMA: A = V^T frag (k=quad*4+j via permuted cols),
      //      B = pf (lane-local). acc layout: row=d (mt*16+quad*4+i), col=qrow.
#pragma unroll
      for (int mt = 0; mt < 8; mt++) {
        const char* vr = VbC + (size_t)(mt * 16 + l15) * 128;
        bf16x8 v01 = *(const bf16x8*)(vr + ((quad * 16) ^ rsw));
        bf16x8 v23 = *(const bf16x8*)(vr + ((64 + quad * 16) ^ rsw));
        bf16x4 va = __builtin_shufflevector(v01, v01, 0, 1, 2, 3);
        bf16x4 vb = __builtin_shufflevector(v01, v01, 4, 5, 6, 7);
        bf16x4 vc = __builtin_shufflevector(v23, v23, 0, 1, 2, 3);
        bf16x4 vd = __builtin_shufflevector(v23, v23, 4, 5, 6, 7);
        acc[mt] = mfma16k16(va, pf[0], acc[mt]);
        acc[mt] = mfma16k16(vb, pf[1], acc[mt]);
        acc[mt] = mfma16k16(vc, pf[2], acc[mt]);
        acc[mt] = mfma16k16(vd, pf[3], acc[mt]);
      }
    }

    // ---- stage round r+1 into the other buffer; single barrier per round.
    if (!last) {
      STAGE(cur ^ 1);
      __syncthreads();
      cur ^= 1;
    }
  }

  {
    const float invl = 1.0f / l_i;
    bf16_t* ob = o + ((size_t)(b * LL + q0 + l15)) * (HQ * DHD) + h * DHD + quad * 4;
#pragma unroll
    for (int mt = 0; mt < 8; mt++) {
      f32x4 a = acc[mt];
      bf16x4 w = {(bf16_t)(a[0] * invl), (bf16_t)(a[1] * invl),
                  (bf16_t)(a[2] * invl), (bf16_t)(a[3] * invl)};
      *(bf16x4*)(ob + mt * 16) = w;
    }
  }
}

extern "C" void kernel_launch(void* const* d_in, const int* in_sizes, int n_in,
                              void* d_out, int out_size, void* d_ws, size_t ws_size,
                              hipStream_t stream) {
  const float* hidden = (const float*)d_in[0];
  const int*   amask  = (const int*)d_in[1];
  const float* Wq     = (const float*)d_in[2];
  const float* Wk     = (const float*)d_in[3];
  const float* Wv     = (const float*)d_in[4];
  const float* Wo     = (const float*)d_in[5];
  float* out = (float*)d_out;

  const int M = BB * LL;           // 4096
  const size_t MB = 1u << 20;
  char* ws = (char*)d_ws;
  bf16_t* hid_b   = (bf16_t*)(ws);            // 16 MB  (B,L,D)
  bf16_t* q_ws    = (bf16_t*)(ws + 16 * MB);  // 16 MB
  bf16_t* attn_ws = (bf16_t*)(ws + 32 * MB);  // 16 MB
  bf16_t* k_ws    = (bf16_t*)(ws + 48 * MB);  //  4 MB
  bf16_t* vt_ws   = (bf16_t*)(ws + 52 * MB);  //  4 MB
  bf16_t* wqkv_b  = (bf16_t*)(ws + 56 * MB);  // 12 MB: Wq(8) + Wk(2) + Wv(2)
  bf16_t* wq_b    = wqkv_b;
  bf16_t* wk_b    = (bf16_t*)(ws + 64 * MB);
  bf16_t* wv_b    = (bf16_t*)(ws + 66 * MB);
  bf16_t* wo_b    = (bf16_t*)(ws + 68 * MB);  //  8 MB
  float*  bias_ws = (float*)(ws);             // 16 KB, aliases hid_b

  CastArgs ca;
  ca.s[0] = hidden; ca.d[0] = hid_b; ca.n[0] = BB * LL * DDIM;
  ca.s[1] = Wq;     ca.d[1] = wq_b;  ca.n[1] = HQ * DHD * DDIM;
  ca.s[2] = Wk;     ca.d[2] = wk_b;  ca.n[2] = HKV * DHD * DDIM;
  ca.s[3] = Wv;     ca.d[3] = wv_b;  ca.n[3] = HKV * DHD * DDIM;
  ca.s[4] = Wo;     ca.d[4] = wo_b;  ca.n[4] = DDIM * DDIM;
  {
    int maxn = BB * LL * DDIM;
    dim3 g((maxn / 8 + 255) / 256, 5);
    cast5_kernel<<<g, 256, 0, stream>>>(ca);
  }

  gemm_tile<3><<<dim3(3072 / 128, M / 128), 256, 0, stream>>>(
      hid_b, wqkv_b, q_ws, k_ws, vt_ws, M, 3072, DDIM);

  {
    int total = BB * LL * (HQ + HKV) * 64 + BB * LL;
    rope_kernel<<<(total + 255) / 256, 256, 0, stream>>>(q_ws, k_ws, amask, bias_ws);
  }

  flash_attn2<<<512, 512, 0, stream>>>(q_ws, k_ws, vt_ws, bias_ws, attn_ws);

  gemm_tile<2><<<dim3(DDIM / 128, M / 128), 256, 0, stream>>>(
      attn_ws, wo_b, (void*)out, nullptr, nullptr, M, DDIM, DDIM);
}